// Round 1
// 235.955 us; speedup vs baseline: 1.1348x; 1.1348x over previous
//
#include <hip/hip_runtime.h>
#include <hip/hip_bf16.h>

#define N_NODES 10000
#define N_EDGES 30000
#define F_NODE  32
#define F_EDGE  8
#define EMB     64
#define HID     16
#define NGRAPH  64

#define M_PAD    10016            // 313 * 32 (GEMM row padding)
#define PRE_GRID 313
#define NCOL     1088             // 1024 U columns + 64 XB columns

typedef __attribute__((ext_vector_type(8))) short short8;   // 8 bf16 = 4 VGPR (MFMA A/B frag)
typedef __attribute__((ext_vector_type(4))) float f32x4;    // MFMA C/D frag

__device__ __forceinline__ unsigned short f2b(float f) {
    __hip_bfloat16 h = __float2bfloat16(f);
    return __builtin_bit_cast(unsigned short, h);
}

// ---------------------------------------------------------------------------
// Prep (fused): edge-MLP hidden for both MLPs; x_p -> bf16; permuted bf16
// weights W2p[j=o*16+h][k] (+ b2 appended as cols 1024..1087); zero XbfB pad.
//   grid = 118 + 1252 + 136 + 272 + 4 = 1782 blocks x 256
// ---------------------------------------------------------------------------
__global__ void k_prep(const float* __restrict__ ea,
                       const float* __restrict__ w1a, const float* __restrict__ b1a,
                       const float* __restrict__ w1b, const float* __restrict__ b1b,
                       float* __restrict__ A0, float* __restrict__ A1,
                       const float* __restrict__ x_p, unsigned short* __restrict__ Xbf0,
                       const float* __restrict__ w20, const float* __restrict__ b20,
                       unsigned short* __restrict__ W2p0,
                       const float* __restrict__ w21, const float* __restrict__ b21,
                       unsigned short* __restrict__ W2p1,
                       unsigned short* __restrict__ XbfB) {
    int b = blockIdx.x, t = threadIdx.x;
    if (b < 118) {                       // edge MLP hidden layers
        int e = b * 256 + t;
        if (e >= N_EDGES) return;
        float f[F_EDGE];
#pragma unroll
        for (int i = 0; i < F_EDGE; i++) f[i] = ea[e * F_EDGE + i];
#pragma unroll
        for (int h = 0; h < HID; h++) {
            float s0 = b1a[h], s1 = b1b[h];
#pragma unroll
            for (int i = 0; i < F_EDGE; i++) {
                s0 += f[i] * w1a[i * HID + h];
                s1 += f[i] * w1b[i * HID + h];
            }
            A0[e * HID + h] = fmaxf(s0, 0.f);
            A1[e * HID + h] = fmaxf(s1, 0.f);
        }
    } else if (b < 1370) {               // x_p -> bf16 (pad rows zeroed)
        int i = (b - 118) * 256 + t;     // i < 320512 = M_PAD*32
        Xbf0[i] = (i < N_NODES * F_NODE) ? f2b(x_p[i]) : (unsigned short)0;
    } else if (b < 1506) {               // W2p0: [j][k] bf16, j=o*16+h, K=32
        int i = (b - 1370) * 256 + t;    // i < 34816 = NCOL*32
        int j = i >> 5, k = i & 31;
        float v = (j < 1024) ? w20[(j & 15) * (F_NODE * EMB) + k * EMB + (j >> 4)]
                             : b20[k * EMB + (j - 1024)];
        W2p0[i] = f2b(v);
    } else if (b < 1778) {               // W2p1: [j][k] bf16, K=64
        int i = (b - 1506) * 256 + t;    // i < 69632 = NCOL*64
        int j = i >> 6, k = i & 63;
        float v = (j < 1024) ? w21[(j & 15) * (EMB * EMB) + k * EMB + (j >> 4)]
                             : b21[k * EMB + (j - 1024)];
        W2p1[i] = f2b(v);
    } else {                             // zero bf16-X pad rows (poison guard)
        int i = (b - 1778) * 256 + t;
        if (i < (M_PAD - N_NODES) * EMB) XbfB[N_NODES * EMB + i] = 0;
    }
}

// ---------------------------------------------------------------------------
// MFMA precompute: C[M_PAD x 1088] = Xbf[M_PAD x K] @ W2p^T, K = 32 or 64.
//   cols < 1024 -> U[n][o*16+h] bf16 (h contiguous for the gather)
//   cols >= 1024 -> XB[n][o] fp32
// Block = 256 thr (4 waves) x 32 rows; wave w owns col-tiles w*17..w*17+16.
// No LDS, no barriers. AGG (and POOL for conv2) zeroing fused.
// ---------------------------------------------------------------------------
template <int K, bool ZERO_POOL>
__global__ void __launch_bounds__(256) k_pre_mfma(const unsigned short* __restrict__ Xbf,
                                                  const unsigned short* __restrict__ W2p,
                                                  unsigned short* __restrict__ U,
                                                  float* __restrict__ XB,
                                                  float* __restrict__ AGG,
                                                  float* __restrict__ POOL) {
    int b = blockIdx.x, t = threadIdx.x;
    int gtid = b * 256 + t;
    for (int i = gtid; i < N_NODES * EMB; i += PRE_GRID * 256) AGG[i] = 0.f;
    if (ZERO_POOL && gtid < NGRAPH * EMB) POOL[gtid] = 0.f;

    int w = t >> 6, l = t & 63;
    int n0 = b * 32;
    int lrow = l & 15;
    int lk = (l >> 4) * 8;               // k-chunk this lane supplies

    short8 a[2][K / 32];
#pragma unroll
    for (int rt = 0; rt < 2; rt++)
#pragma unroll
        for (int kk = 0; kk < K / 32; kk++)
            a[rt][kk] = *reinterpret_cast<const short8*>(
                Xbf + (size_t)(n0 + rt * 16 + lrow) * K + kk * 32 + lk);

    for (int ct = 0; ct < 17; ct++) {
        int c0 = (w * 17 + ct) * 16;
        short8 bf[K / 32];
#pragma unroll
        for (int kk = 0; kk < K / 32; kk++)
            bf[kk] = *reinterpret_cast<const short8*>(
                W2p + (size_t)(c0 + lrow) * K + kk * 32 + lk);
#pragma unroll
        for (int rt = 0; rt < 2; rt++) {
            f32x4 acc = {0.f, 0.f, 0.f, 0.f};
#pragma unroll
            for (int kk = 0; kk < K / 32; kk++)
                acc = __builtin_amdgcn_mfma_f32_16x16x32_bf16(a[rt][kk], bf[kk], acc, 0, 0, 0);
            int r0 = n0 + rt * 16 + (l >> 4) * 4;   // D: row=(l>>4)*4+r, col=l&15
            int col = c0 + lrow;
            if (c0 < 1024) {
#pragma unroll
                for (int r = 0; r < 4; r++)
                    U[(size_t)(r0 + r) * 1024 + col] = f2b(acc[r]);
            } else {
#pragma unroll
                for (int r = 0; r < 4; r++)
                    XB[(size_t)(r0 + r) * EMB + (col - 1024)] = acc[r];
            }
        }
    }
}

// ---------------------------------------------------------------------------
// Gather: msg[e,o] = XB[s,o] + sum_h A[e,h]*U[s][o*16+h]; atomicAdd into AGG.
// Lane o: 2x dwordx4 (16 contiguous bf16) + 1 dword; A via SGPR s_loads.
// ---------------------------------------------------------------------------
__global__ void __launch_bounds__(256) k_gather(const float* __restrict__ A,
                                                const unsigned short* __restrict__ U,
                                                const float* __restrict__ XB,
                                                const int* __restrict__ src,
                                                const int* __restrict__ dst,
                                                float* __restrict__ AGG) {
    int e = blockIdx.x * 4 + (threadIdx.x >> 6);
    e = __builtin_amdgcn_readfirstlane(e);
    if (e >= N_EDGES) return;
    int o = threadIdx.x & 63;
    int s = src[e], d = dst[e];
    const uint4* up = reinterpret_cast<const uint4*>(U + (size_t)s * 1024 + o * 16);
    uint4 u0 = up[0];
    uint4 u1 = up[1];
    const float* Ae = A + e * HID;       // uniform address -> scalar loads
    float a[HID];
#pragma unroll
    for (int h = 0; h < HID; h++) a[h] = Ae[h];
    float m = XB[s * EMB + o];
#define ACC2(wrd, h)                                                              \
    m = fmaf(__builtin_bit_cast(float, (unsigned)(wrd) << 16), a[h], m);          \
    m = fmaf(__builtin_bit_cast(float, (unsigned)(wrd) & 0xffff0000u), a[h + 1], m);
    ACC2(u0.x, 0) ACC2(u0.y, 2) ACC2(u0.z, 4) ACC2(u0.w, 6)
    ACC2(u1.x, 8) ACC2(u1.y, 10) ACC2(u1.z, 12) ACC2(u1.w, 14)
#undef ACC2
    atomicAdd(&AGG[(size_t)d * EMB + o], m);
}

// ---------------------------------------------------------------------------
// Node update (unchanged math); optionally emits bf16 X for next conv's MFMA.
// ---------------------------------------------------------------------------
template <int IN, bool POOLING, bool WBF>
__global__ void k_update(const float* __restrict__ xin, const float* __restrict__ AGG,
                         const float* __restrict__ root, const float* __restrict__ bias,
                         const int* __restrict__ batch,
                         float* __restrict__ Xout, unsigned short* __restrict__ Xbf,
                         unsigned int* __restrict__ POOL) {
    int n0 = blockIdx.x * 4;
    __shared__ float xr[4][IN];
    for (int idx = threadIdx.x; idx < 4 * IN; idx += 256)
        xr[idx / IN][idx % IN] = xin[n0 * IN + idx];
    __syncthreads();
    int j = threadIdx.x >> 6, t = threadIdx.x & 63;
    int n = n0 + j;
    float s = AGG[n * EMB + t] + bias[t];
#pragma unroll
    for (int i = 0; i < IN; i++) s += xr[j][i] * root[i * EMB + t];
    s = fmaxf(s, 0.f);
    Xout[n * EMB + t] = s;
    if (WBF) Xbf[n * EMB + t] = f2b(s);
    if (POOLING) atomicMax(&POOL[batch[n] * EMB + t], __float_as_uint(s));
}

// --- Head: out[g] = (pooled[g]@lin0_w + lin0_b) @ lin1_w + lin1_b
__global__ void k_head(const float* __restrict__ POOL,
                       const float* __restrict__ l0w, const float* __restrict__ l0b,
                       const float* __restrict__ l1w, const float* __restrict__ l1b,
                       float* __restrict__ out) {
    __shared__ float P[NGRAPH * EMB];
    int t = threadIdx.x; // 64
    for (int k = 0; k < NGRAPH; k++) P[k * EMB + t] = POOL[k * EMB + t];
    __syncthreads();
    int g = t;
    float acc = l1b[0];
    for (int o2 = 0; o2 < EMB; o2++) {
        float h = l0b[o2];
        for (int o = 0; o < EMB; o++) h += P[g * EMB + o] * l0w[o * EMB + o2];
        acc += h * l1w[o2];
    }
    out[g] = acc;
}

extern "C" void kernel_launch(void* const* d_in, const int* in_sizes, int n_in,
                              void* d_out, int out_size, void* d_ws, size_t ws_size,
                              hipStream_t stream) {
    const float* x_p    = (const float*)d_in[0];
    const float* ea     = (const float*)d_in[2];
    const int*   eidx   = (const int*)d_in[4];
    const int*   batch  = (const int*)d_in[5];
    const float* nn0_w1 = (const float*)d_in[6];
    const float* nn0_b1 = (const float*)d_in[7];
    const float* nn0_w2 = (const float*)d_in[8];
    const float* nn0_b2 = (const float*)d_in[9];
    const float* nn1_w1 = (const float*)d_in[10];
    const float* nn1_b1 = (const float*)d_in[11];
    const float* nn1_w2 = (const float*)d_in[12];
    const float* nn1_b2 = (const float*)d_in[13];
    const float* root0  = (const float*)d_in[14];
    const float* bias0  = (const float*)d_in[15];
    const float* root1  = (const float*)d_in[16];
    const float* bias1  = (const float*)d_in[17];
    const float* root2  = (const float*)d_in[18];
    const float* bias2  = (const float*)d_in[19];
    const float* lin0_w = (const float*)d_in[20];
    const float* lin0_b = (const float*)d_in[21];
    const float* lin1_w = (const float*)d_in[22];
    const float* lin1_b = (const float*)d_in[23];

    const int* src = eidx;             // edge_index_p[0]
    const int* dst = eidx + N_EDGES;   // edge_index_p[1]

    // workspace layout (~35 MB)
    char* ws = (char*)d_ws;
    float* A0           = (float*)ws;          ws += (size_t)N_EDGES * HID * 4;
    float* A1           = (float*)ws;          ws += (size_t)N_EDGES * HID * 4;
    unsigned short* W2p0 = (unsigned short*)ws; ws += (size_t)NCOL * F_NODE * 2;
    unsigned short* W2p1 = (unsigned short*)ws; ws += (size_t)NCOL * EMB * 2;
    unsigned short* Xbf0 = (unsigned short*)ws; ws += (size_t)M_PAD * F_NODE * 2;
    unsigned short* XbfB = (unsigned short*)ws; ws += (size_t)M_PAD * EMB * 2;
    unsigned short* U    = (unsigned short*)ws; ws += (size_t)M_PAD * 1024 * 2;
    float* XB           = (float*)ws;          ws += (size_t)M_PAD * EMB * 4;
    float* X            = (float*)ws;          ws += (size_t)N_NODES * EMB * 4;
    float* AGG          = (float*)ws;          ws += (size_t)N_NODES * EMB * 4;
    float* POOL         = (float*)ws;          ws += (size_t)NGRAPH * EMB * 4;

    const int UPD_GRID = N_NODES / 4;          // 2500
    const int GTH_GRID = N_EDGES / 4;          // 7500

    // prep: edge hiddens + bf16 conversions + permuted weights
    k_prep<<<1782, 256, 0, stream>>>(ea, nn0_w1, nn0_b1, nn1_w1, nn1_b1, A0, A1,
                                     x_p, Xbf0, nn0_w2, nn0_b2, W2p0,
                                     nn1_w2, nn1_b2, W2p1, XbfB);

    // ---- conv 0 (K = F_NODE = 32)
    k_pre_mfma<F_NODE, false><<<PRE_GRID, 256, 0, stream>>>(Xbf0, W2p0, U, XB, AGG, POOL);
    k_gather<<<GTH_GRID, 256, 0, stream>>>(A0, U, XB, src, dst, AGG);
    k_update<F_NODE, false, true><<<UPD_GRID, 256, 0, stream>>>(x_p, AGG, root0, bias0, batch,
                                                                X, XbfB, (unsigned int*)POOL);

    // ---- conv 1 (K = EMB = 64)
    k_pre_mfma<EMB, false><<<PRE_GRID, 256, 0, stream>>>(XbfB, W2p1, U, XB, AGG, POOL);
    k_gather<<<GTH_GRID, 256, 0, stream>>>(A1, U, XB, src, dst, AGG);
    k_update<EMB, false, true><<<UPD_GRID, 256, 0, stream>>>(X, AGG, root1, bias1, batch,
                                                             X, XbfB, (unsigned int*)POOL);

    // ---- conv 2 (POOL zeroed in precompute, max-pool in update)
    k_pre_mfma<EMB, true><<<PRE_GRID, 256, 0, stream>>>(XbfB, W2p1, U, XB, AGG, POOL);
    k_gather<<<GTH_GRID, 256, 0, stream>>>(A1, U, XB, src, dst, AGG);
    k_update<EMB, true, false><<<UPD_GRID, 256, 0, stream>>>(X, AGG, root2, bias2, batch,
                                                             X, XbfB, (unsigned int*)POOL);

    // ---- head
    k_head<<<1, 64, 0, stream>>>(POOL, lin0_w, lin0_b, lin1_w, lin1_b, (float*)d_out);
}